// Round 5
// baseline (446.415 us; speedup 1.0000x reference)
//
#include <hip/hip_runtime.h>
#include <hip/hip_cooperative_groups.h>
#include <math.h>

namespace cg = cooperative_groups;

#define NTOT 16384
#define NSEG 2048

// ws float offsets (same layout as R4)
#define OFF_HH   0ull         // hh [4][8][2048][64] = 4194304 (hc [8][2048][64] reuses)
#define OFF_XC   4194304ull   // xc [16384][256] = 4194304 (TAS/TSA/TSS time-share)
#define OFF_S1H  8388608ull
#define OFF_S2H  8454144ull
#define OFF_S1O  8519680ull
#define OFF_S2O  8536064ull
#define OFF_SVAL 8552448ull
#define OFF_WN   8617984ull
#define OFF_SIDX 8683520ull
#define OFF_VAS  8749056ull
#define OFF_CSA  9277440ull
#define OFF_CSS  9281568ull
#define OFF_SCA  9285696ull
#define OFF_SCS  9351232ull
#define OFF_AS   9416768ull   // -> end 17805376 floats

__device__ inline unsigned long long pack_key(float v, int idx) {
    unsigned u = __float_as_uint(v);
    u = (u & 0x80000000u) ? ~u : (u | 0x80000000u);
    return ((unsigned long long)u << 32) | (unsigned)idx;
}
__device__ inline float unpack_key(unsigned long long k) {
    unsigned u = (unsigned)(k >> 32);
    u = (u & 0x80000000u) ? (u ^ 0x80000000u) : ~u;
    return __uint_as_float(u);
}
__device__ inline unsigned long long shfl_xor_u64(unsigned long long x, int mask) {
    unsigned lo = (unsigned)x, hi = (unsigned)(x >> 32);
    lo = (unsigned)__shfl_xor((int)lo, mask, 64);
    hi = (unsigned)__shfl_xor((int)hi, mask, 64);
    return ((unsigned long long)hi << 32) | lo;
}

// ---------------- per-chunk table build body (1 wave = 1 chunk) ----------------
__device__ __forceinline__ void tabw_body(const float* __restrict__ Vp, int t, int c, int lane,
                                          const int* __restrict__ g_sidx, const float* __restrict__ g_wN,
                                          float* __restrict__ AS,
                                          float* __restrict__ SCA, float* __restrict__ SCS,
                                          float* __restrict__ TAS,
                                          float* __restrict__ TSA, float* __restrict__ TSS) {
    const int base = c * 16;
    const int* sidx = g_sidx + (size_t)t * NSEG + base;
    const float* wnp = g_wN + (size_t)t * NSEG + base;
    float wn[16], vv[16];
#pragma unroll
    for (int j = 0; j < 16; ++j) wn[j] = wnp[j];
#pragma unroll
    for (int j = 0; j < 16; ++j) vv[j] = Vp[(size_t)sidx[j] * 64 + lane];
    float* ASp = AS + (size_t)t * NSEG * 128;
    float accA = 0.f, scaA = 0.f;
#pragma unroll
    for (int j = 0; j < 16; ++j) {
        size_t pos = base + j;
        ASp[pos * 128 + lane] = accA;
        if (lane == 0) SCA[(size_t)t * NSEG + pos] = scaA;
        accA += wn[j] * vv[j]; scaA += wn[j];
    }
    TAS[((size_t)t * 128 + c) * 128 + lane] = accA;
    if (lane == 0) TSA[t * 128 + c] = scaA;
    float accS = 0.f, scaS = 0.f;
#pragma unroll
    for (int j = 15; j >= 0; --j) {
        float wq = wn[j], w2 = wq * wq, wp = w2 * w2 * wq;
        accS += wp * vv[j]; scaS += wp;
        size_t pos = base + j;
        ASp[pos * 128 + 64 + lane] = accS;
        if (lane == 0) SCS[(size_t)t * NSEG + pos] = scaS;
    }
    TAS[((size_t)t * 128 + c) * 128 + 64 + lane] = accS;
    if (lane == 0) TSS[t * 128 + c] = scaS;
}

// ---------------- per-task chunk-total scan body (threads 0..129) ----------------
__device__ __forceinline__ void scan_body(int t, int tid,
                                          const float* __restrict__ TAS,
                                          const float* __restrict__ TSA, const float* __restrict__ TSS,
                                          float* __restrict__ VAS,
                                          float* __restrict__ CSA, float* __restrict__ CSS) {
    const float* T = TAS + (size_t)t * 128 * 128;
    float* Vo = VAS + (size_t)t * 129 * 128;
    if (tid < 64) {
        float run = 0.f;
#pragma unroll 4
        for (int c = 0; c < 128; ++c) { Vo[c * 128 + tid] = run; run += T[c * 128 + tid]; }
        Vo[128 * 128 + tid] = run;
    } else if (tid < 128) {
        float run = 0.f;
#pragma unroll 4
        for (int c = 127; c >= 0; --c) { Vo[c * 128 + tid] = run; run += T[c * 128 + tid]; }
    } else if (tid == 128) {
        float run = 0.f;
        for (int c = 0; c < 128; ++c) { CSA[t * 129 + c] = run; run += TSA[t * 128 + c]; }
        CSA[t * 129 + 128] = run;
    } else if (tid == 129) {
        float run = 0.f;
        for (int c = 127; c >= 0; --c) { CSS[t * 129 + c] = run; run += TSS[t * 128 + c]; }
    }
}

// ---------------- query body: 1 wave handles 16 queries starting at q0 ----------------
template <int MODE>
__device__ __forceinline__ void query_body(int t, int q0, int lane, float M2,
                                           const float* __restrict__ sval,
                                           const float* __restrict__ s1p,
                                           float* __restrict__ outp, int ostride,
                                           const float* __restrict__ AS,
                                           const float* __restrict__ SCA, const float* __restrict__ SCS,
                                           const float* __restrict__ VAS,
                                           const float* __restrict__ CSA, const float* __restrict__ CSS) {
    const float* ASp = AS + (size_t)t * NSEG * 128;
    const float* VASp = VAS + (size_t)t * 129 * 128;
    const float* scA = SCA + (size_t)t * NSEG;
    const float* scS = SCS + (size_t)t * NSEG;
    const float* csA = CSA + (size_t)t * 129;
    const float* csS = CSS + (size_t)t * 129;
    int myq = q0 + (lane & 15);
    float s1v = s1p[myq];
    float th = -s1v;
    int lo = 0, hi = NSEG;
    while (lo < hi) { int mid = (lo + hi) >> 1; if (sval[mid] <= th) lo = mid + 1; else hi = mid; }
#pragma unroll 4
    for (int j = 0; j < 16; ++j) {
        int k = __shfl(lo, j, 64);
        float s1q = __shfl(s1v, j, 64);
        float accA, scaA, accS, scaS;
        if (k < NSEG) {
            const int c = k >> 4;
            const float* rowP = ASp + (size_t)k * 128;
            const float* rowC = VASp + (size_t)c * 128;
            accA = rowP[lane] + rowC[lane];
            accS = rowP[64 + lane] + rowC[64 + lane];
            scaA = scA[k] + csA[c];
            scaS = scS[k] + csS[c];
        } else {
            accA = VASp[128 * 128 + lane]; scaA = csA[128];
            accS = 0.f; scaS = 0.f;
        }
        float cc = __expf(-0.8f * fmaxf(s1q + M2, 0.f));
        float o = (accS + cc * accA) / (scaS + cc * scaA);
        o = o > 0.f ? o : expm1f(o);  // ELU
        int q = q0 + j;
        if (MODE == 0) {
            outp[(size_t)q * ostride + lane] = o;
        } else {
            float m = o;
#pragma unroll
            for (int off = 32; off; off >>= 1) m = fmaxf(m, __shfl_xor(m, off, 64));
            float e = __expf(o - m);
#pragma unroll
            for (int off = 32; off; off >>= 1) e += __shfl_xor(e, off, 64);
            outp[(size_t)q * ostride + lane] = o - m - __logf(e);
        }
    }
}

// ---------------- sort body: one 1024-thread block sorts one task ----------------
__device__ __forceinline__ void sort_body(const float* __restrict__ s2p, int t, int tid,
                                          unsigned long long* sA, unsigned long long* sB, float* sM2,
                                          float* __restrict__ g_sval, int* __restrict__ g_sidx,
                                          float* __restrict__ g_wN) {
    unsigned long long a0 = pack_key(s2p[tid], tid);
    unsigned long long a1 = pack_key(s2p[tid + 1024], tid + 1024);
    int p = 0;
    for (int k = 2; k <= 2048; k <<= 1) {
        const bool up0 = (tid & k) == 0;
        const bool up1 = (((tid + 1024) & k) == 0);
        for (int j = k >> 1; j > 0; j >>= 1) {
            if (j >= 1024) {
                unsigned long long lo = a0 < a1 ? a0 : a1;
                unsigned long long hi = a0 < a1 ? a1 : a0;
                a0 = up0 ? lo : hi;
                a1 = up0 ? hi : lo;
            } else if (j >= 64) {
                sA[p * 1024 + tid] = a0; sB[p * 1024 + tid] = a1;
                __syncthreads();
                unsigned long long q0 = sA[p * 1024 + (tid ^ j)], q1 = sB[p * 1024 + (tid ^ j)];
                bool lower = (tid & j) == 0;
                a0 = ((a0 < q0) == (lower == up0)) ? a0 : q0;
                a1 = ((a1 < q1) == (lower == up1)) ? a1 : q1;
                p ^= 1;
            } else {
                unsigned long long q0 = shfl_xor_u64(a0, j);
                unsigned long long q1 = shfl_xor_u64(a1, j);
                bool lower = (tid & j) == 0;
                a0 = ((a0 < q0) == (lower == up0)) ? a0 : q0;
                a1 = ((a1 < q1) == (lower == up1)) ? a1 : q1;
            }
        }
    }
    float v0 = unpack_key(a0), v1 = unpack_key(a1);
    if (tid == 1023) *sM2 = v1;
    __syncthreads();
    const float M2 = *sM2;
    int i0 = (int)(unsigned)(a0 & 0xffffffffu);
    int i1 = (int)(unsigned)(a1 & 0xffffffffu);
    float w0 = __expf(0.2f * (v0 - M2));
    float w1 = __expf(0.2f * (v1 - M2));
    size_t o = (size_t)t * NSEG;
    g_sval[o + tid] = v0; g_sval[o + tid + 1024] = v1;
    g_sidx[o + tid] = i0; g_sidx[o + tid + 1024] = i1;
    g_wN[o + tid] = w0;   g_wN[o + tid + 1024] = w1;
}

// ================= cooperative mega-kernel: the whole pipeline, 1 launch =================
__global__ __launch_bounds__(1024) void mega_k(const float* __restrict__ X,
                                               const float* __restrict__ Wh,
                                               const float* __restrict__ aH,
                                               const float* __restrict__ Wo,
                                               const float* __restrict__ aO,
                                               float* __restrict__ w,
                                               float* __restrict__ outg) {
    cg::grid_group grid = cg::this_grid();
    __shared__ __align__(16) char smem[139264];
    __shared__ float sM2;
    const int tid = threadIdx.x;
    const int blk = blockIdx.x;

    float* hh = w + OFF_HH;
    float* xc = w + OFF_XC;
    float* hc = w + OFF_HH;              // reuse: hh dead after tabw1
    float* s1h = w + OFF_S1H;
    float* s2h = w + OFF_S2H;
    float* s1o = w + OFF_S1O;
    float* s2o = w + OFF_S2O;
    float* g_sval = w + OFF_SVAL;
    float* g_wN = w + OFF_WN;
    int* g_sidx = (int*)(w + OFF_SIDX);
    float* TAS = w + OFF_XC;             // time-shared with xc
    float* TSA = w + OFF_XC + 524288;
    float* TSS = w + OFF_XC + 528384;
    float* VAS = w + OFF_VAS;
    float* CSA = w + OFF_CSA;
    float* CSS = w + OFF_CSS;
    float* SCA = w + OFF_SCA;
    float* SCS = w + OFF_SCS;
    float* AS = w + OFF_AS;

    // ---------- phase 1: gemm1 — 4 sub-tiles (256 thr each) per block; hh head-major ----------
    {
        const int sub = tid >> 8, st = tid & 255;
        const int tile = sub * 256 + blk;      // 0..1023
        const int h = tile & 3, bm = tile >> 2;
        float (*As)[68] = (float (*)[68])(smem + (size_t)sub * 34816);
        float (*Bs)[68] = (float (*)[68])(smem + (size_t)sub * 34816 + 17408);
        const int c0 = st & 63, r0 = st >> 6;
#pragma unroll
        for (int r = 0; r < 16; ++r) {
            int row = r0 + r * 4;
            As[c0][row] = X[(size_t)(bm * 64 + row) * 64 + c0];
            Bs[row][c0] = Wh[h * 4096 + row * 64 + c0];
        }
        __syncthreads();
        const int tx = st & 15, ty = st >> 4;
        const int m0 = ty * 4, n0 = tx * 4;
        float acc[4][4] = {};
#pragma unroll
        for (int kk = 0; kk < 64; ++kk) {
            float4 a = *(const float4*)&As[kk][m0];
            float4 b = *(const float4*)&Bs[kk][n0];
            acc[0][0] += a.x * b.x; acc[0][1] += a.x * b.y; acc[0][2] += a.x * b.z; acc[0][3] += a.x * b.w;
            acc[1][0] += a.y * b.x; acc[1][1] += a.y * b.y; acc[1][2] += a.y * b.z; acc[1][3] += a.y * b.w;
            acc[2][0] += a.z * b.x; acc[2][1] += a.z * b.y; acc[2][2] += a.z * b.z; acc[2][3] += a.z * b.w;
            acc[3][0] += a.w * b.x; acc[3][1] += a.w * b.y; acc[3][2] += a.w * b.z; acc[3][3] += a.w * b.w;
        }
        const int g = bm >> 5;
        const int nb = (bm * 64) & 2047;
#pragma unroll
        for (int i = 0; i < 4; ++i) {
            float4 v = make_float4(acc[i][0], acc[i][1], acc[i][2], acc[i][3]);
            *(float4*)&hh[(((size_t)h * 8 + g) * NSEG + nb + m0 + i) * 64 + n0] = v;
        }
#pragma unroll
        for (int i = 0; i < 4; ++i) {
            float p1 = 0.f, p2 = 0.f;
#pragma unroll
            for (int jj = 0; jj < 4; ++jj) {
                p1 += acc[i][jj] * aH[h * 128 + n0 + jj];
                p2 += acc[i][jj] * aH[h * 128 + 64 + n0 + jj];
            }
#pragma unroll
            for (int off = 8; off; off >>= 1) {
                p1 += __shfl_xor(p1, off, 16);
                p2 += __shfl_xor(p2, off, 16);
            }
            if (tx == 0) {
                s1h[h * NTOT + bm * 64 + m0 + i] = p1;
                s2h[h * NTOT + bm * 64 + m0 + i] = p2;
            }
        }
    }
    grid.sync();

    // ---------- phase 2: sort layer 1 — blocks 0..31, one task each ----------
    if (blk < 32) {
        unsigned long long* sA = (unsigned long long*)smem;
        unsigned long long* sB = sA + 2048;
        const int t = blk, g = t >> 2, h = t & 3;
        sort_body(s2h + (size_t)h * NTOT + (size_t)g * NSEG, t, tid, sA, sB, &sM2,
                  g_sval, g_sidx, g_wN);
    }
    grid.sync();

    // ---------- phase 3: tabw layer 1 — 1 chunk per wave (4096 = 256 blk x 16 waves) ----------
    {
        const int wv = tid >> 6, lane = tid & 63;
        const int chunk = blk * 16 + wv;
        const int t = chunk >> 7, c = chunk & 127;
        const int g = t >> 2, h = t & 3;
        const float* Vp = hh + ((size_t)h * 8 + g) * NSEG * 64;
        tabw_body(Vp, t, c, lane, g_sidx, g_wN, AS, SCA, SCS, TAS, TSA, TSS);
    }
    grid.sync();

    // ---------- phase 4: scan layer 1 — blocks 0..31 ----------
    if (blk < 32) scan_body(blk, tid, TAS, TSA, TSS, VAS, CSA, CSS);
    grid.sync();

    // ---------- phase 5: query layer 1 -> xc ; 8 blocks per task ----------
    {
        float* sval = (float*)smem;
        const int t = blk >> 3, u8 = blk & 7;
        const int g = t >> 2, h = t & 3;
        const float4* sv4 = (const float4*)(g_sval + (size_t)t * NSEG);
        for (int i = tid; i < NSEG / 4; i += 1024) ((float4*)sval)[i] = sv4[i];
        __syncthreads();
        const float M2 = sval[NSEG - 1];
        const int lane = tid & 63, wv = tid >> 6;
        const int q0 = u8 * 256 + wv * 16;
        query_body<0>(t, q0, lane, M2, sval,
                      s1h + (size_t)h * NTOT + (size_t)g * NSEG,
                      xc + (size_t)g * NSEG * 256 + h * 64, 256,
                      AS, SCA, SCS, VAS, CSA, CSS);
    }
    grid.sync();

    // ---------- phase 6: gemm2 — 512 BM=32 tiles on subs 0..1 of every block ----------
    {
        const int sub = tid >> 8, st = tid & 255;
        const int tile = sub * 256 + blk;      // valid when < 512
        const bool valid = tile < 512;
        const int bm = tile;
        float (*As2)[34] = (float (*)[34])(smem + (size_t)sub * 26112);
        float (*Bs2)[68] = (float (*)[68])(smem + (size_t)sub * 26112 + 8704);
        const int c0 = st & 63, r0 = st >> 6;
        const int tx = st & 15, ty = st >> 4;
        const int m0 = ty * 2, n0 = tx * 4;
        float acc[2][4] = {};
        for (int kt = 0; kt < 4; ++kt) {
            if (valid) {
#pragma unroll
                for (int r = 0; r < 8; ++r) {
                    int row = r0 + r * 4;
                    As2[c0][row] = xc[(size_t)(bm * 32 + row) * 256 + kt * 64 + c0];
                }
#pragma unroll
                for (int r = 0; r < 16; ++r) {
                    int row = r0 + r * 4;
                    Bs2[row][c0] = Wo[(kt * 64 + row) * 64 + c0];
                }
            }
            __syncthreads();
            if (valid) {
#pragma unroll
                for (int kk = 0; kk < 64; ++kk) {
                    float2 a = *(const float2*)&As2[kk][m0];
                    float4 b = *(const float4*)&Bs2[kk][n0];
                    acc[0][0] += a.x * b.x; acc[0][1] += a.x * b.y; acc[0][2] += a.x * b.z; acc[0][3] += a.x * b.w;
                    acc[1][0] += a.y * b.x; acc[1][1] += a.y * b.y; acc[1][2] += a.y * b.z; acc[1][3] += a.y * b.w;
                }
            }
            __syncthreads();
        }
        if (valid) {
#pragma unroll
            for (int i = 0; i < 2; ++i) {
                float4 v = make_float4(acc[i][0], acc[i][1], acc[i][2], acc[i][3]);
                *(float4*)&hc[(size_t)(bm * 32 + m0 + i) * 64 + n0] = v;
            }
#pragma unroll
            for (int i = 0; i < 2; ++i) {
                float p1 = 0.f, p2 = 0.f;
#pragma unroll
                for (int jj = 0; jj < 4; ++jj) {
                    p1 += acc[i][jj] * aO[n0 + jj];
                    p2 += acc[i][jj] * aO[64 + n0 + jj];
                }
#pragma unroll
                for (int off = 8; off; off >>= 1) {
                    p1 += __shfl_xor(p1, off, 16);
                    p2 += __shfl_xor(p2, off, 16);
                }
                if (tx == 0) {
                    s1o[bm * 32 + m0 + i] = p1;
                    s2o[bm * 32 + m0 + i] = p2;
                }
            }
        }
    }
    grid.sync();

    // ---------- phase 7: sort layer 2 — blocks 0..7 ----------
    if (blk < 8) {
        unsigned long long* sA = (unsigned long long*)smem;
        unsigned long long* sB = sA + 2048;
        const int t = blk;
        sort_body(s2o + (size_t)t * NSEG, t, tid, sA, sB, &sM2,
                  g_sval, g_sidx, g_wN);
    }
    grid.sync();

    // ---------- phase 8: tabw layer 2 — 1024 chunks on waves 0..3 of every block ----------
    {
        const int wv = tid >> 6, lane = tid & 63;
        if (wv < 4) {
            const int chunk = blk * 4 + wv;
            const int t = chunk >> 7, c = chunk & 127;
            const float* Vp = hc + (size_t)t * NSEG * 64;
            tabw_body(Vp, t, c, lane, g_sidx, g_wN, AS, SCA, SCS, TAS, TSA, TSS);
        }
    }
    grid.sync();

    // ---------- phase 9: scan layer 2 — blocks 0..7 ----------
    if (blk < 8) scan_body(blk, tid, TAS, TSA, TSS, VAS, CSA, CSS);
    grid.sync();

    // ---------- phase 10: query layer 2 -> out ; 32 blocks per task, waves 0..3 ----------
    {
        float* sval = (float*)smem;
        const int t = blk >> 5, u = blk & 31;
        const float4* sv4 = (const float4*)(g_sval + (size_t)t * NSEG);
        for (int i = tid; i < NSEG / 4; i += 1024) ((float4*)sval)[i] = sv4[i];
        __syncthreads();
        const float M2 = sval[NSEG - 1];
        const int lane = tid & 63, wv = tid >> 6;
        if (wv < 4) {
            const int q0 = u * 64 + wv * 16;
            query_body<1>(t, q0, lane, M2, sval,
                          s1o + (size_t)t * NSEG,
                          outg + (size_t)t * NSEG * 64, 64,
                          AS, SCA, SCS, VAS, CSA, CSS);
        }
    }
}

extern "C" void kernel_launch(void* const* d_in, const int* in_sizes, int n_in,
                              void* d_out, int out_size, void* d_ws, size_t ws_size,
                              hipStream_t stream) {
    const float* h_states = (const float*)d_in[0];
    const float* W_heads = (const float*)d_in[1];
    const float* a_heads = (const float*)d_in[2];
    const float* W_out = (const float*)d_in[3];
    const float* a_out = (const float*)d_in[4];
    float* w = (float*)d_ws;
    float* outp = (float*)d_out;

    void* args[] = {(void*)&h_states, (void*)&W_heads, (void*)&a_heads,
                    (void*)&W_out, (void*)&a_out, (void*)&w, (void*)&outp};
    hipLaunchCooperativeKernel((const void*)mega_k, dim3(256), dim3(1024),
                               args, 0, stream);
}